// Round 13
// baseline (178.492 us; speedup 1.0000x reference)
//
#include <hip/hip_runtime.h>
#include <hip/hip_bf16.h>
#include <stdint.h>

// ---------------- constants ----------------
constexpr int Nn = 8192;
constexpr int Dd = 1024;
constexpr float kAlpha = 0.1f;
constexpr float kEps = 1e-7f;
constexpr float kInf = 3.0e38f;

constexpr int BM = 128, BN = 128, BK = 32;
constexpr int NB = Nn / BM;               // 64 row/col blocks
constexpr int NPAIR = NB * (NB + 1) / 2;  // 2080 upper-triangle tile pairs
constexpr int NT = Dd / BK;               // 32 K-steps

// Hb is stored K-TILED: [rowBlk 64][kt 32][row 128][k 32] — each 128x32 tile
// is a contiguous 8 KB blob (4096 shorts). Offset(row,k) =
//   ((row>>7)*32 + (k>>5))*4096 + (row&127)*32 + (k&31)
constexpr int TILE_SH = 4096;             // shorts per 8 KB tile

using bfx8 = __attribute__((ext_vector_type(8))) __bf16;   // MFMA A/B frag (4 VGPRs)
using f32x4 = __attribute__((ext_vector_type(4))) float;   // MFMA C/D frag

__device__ __forceinline__ unsigned short f2bf(float f) {
  union { float f; unsigned int u; } v; v.f = f;
  unsigned int u = v.u;
  u = u + 0x7fffu + ((u >> 16) & 1u);  // RNE
  return (unsigned short)(u >> 16);
}

__device__ __forceinline__ void min2_insert(float& m1, float& m2, float x) {
  const float lo = fminf(m1, x);
  const float hi = fmaxf(m1, x);
  m1 = lo;
  m2 = fminf(m2, hi);
}

__device__ __forceinline__ void min2_merge(float& m1, float& m2, float o1, float o2) {
  m2 = fminf(fminf(m2, o2), fmaxf(m1, o1));
  m1 = fminf(m1, o1);
}

// ---------------- prep: fp32 -> bf16 (K-tiled) + row sq-norms, coalesced ----
// 256 blocks x 256 threads; block owns 32 rows x full K. Per k-slice of 32:
// 8 threads/row read one 128B line (float4 each) and the block writes one
// 2 KB fully-linear chunk of the destination tile (byte addr = t*8).
// Old layout wrote 64B half-line scatter (8 chunks/wave/iter) — ~2x write
// cost on 16 MB. xn via 8-lane shuffle partial sums. Also zeroes the
// merge-ticket each graph replay (runs first on the stream).
__global__ __launch_bounds__(256) void prep_kernel(const float* __restrict__ H,
                                                   unsigned short* __restrict__ Hb,
                                                   float* __restrict__ xn,
                                                   unsigned int* __restrict__ gticket) {
  if (blockIdx.x == 0 && threadIdx.x == 0) *gticket = 0u;
  const int t = threadIdx.x;
  const int rloc = t >> 3;                 // 0..31: row within block
  const int kq = t & 7;                    // 8 threads per row
  const int row = blockIdx.x * 32 + rloc;
  const float4* src = (const float4*)(H + (size_t)row * Dd);
  unsigned short* tileBase =
      Hb + ((size_t)(row >> 7) * 32) * TILE_SH + (row & 127) * 32;
  float acc = 0.f;
#pragma unroll 4
  for (int ks = 0; ks < 32; ++ks) {
    float4 v = src[ks * 8 + kq];           // 8 threads -> 128B line per row
    acc = fmaf(v.x, v.x, acc);
    acc = fmaf(v.y, v.y, acc);
    acc = fmaf(v.z, v.z, acc);
    acc = fmaf(v.w, v.w, acc);
    ushort4 o;
    o.x = f2bf(v.x); o.y = f2bf(v.y); o.z = f2bf(v.z); o.w = f2bf(v.w);
    *(ushort4*)(tileBase + (size_t)ks * TILE_SH + kq * 4) = o;  // t*8B linear
  }
  // reduce the 8 per-row partials (lane bits 0..2)
#pragma unroll
  for (int off = 1; off < 8; off <<= 1) acc += __shfl_xor(acc, off, 64);
  if (kq == 0) xn[row] = acc;
}

// ---------------- main: symmetric fused GEMM + triplet reductions ----------------
// UNCHANGED from round 12 (best verified: ~100us, MfmaUtil 29, VGPR 64+64,
// 4 blocks/CU). K-tiled Hb staging (full-line L2 requests, r10 win) +
// per-m low-register epilogue (r12 win) + both-sides XOR swizzle + XCD
// swizzle.
__global__ __launch_bounds__(256, 4) void triplet_main(
    const unsigned short* __restrict__ Hb, const float* __restrict__ xn,
    const int* __restrict__ lab, float* __restrict__ wsMax,
    float* __restrict__ wsM1, float* __restrict__ wsM2) {
  __shared__ __align__(16) unsigned char smem[32768];  // 2 x (8KB A + 8KB B)

  const int tid = threadIdx.x;
  const int wave = tid >> 6;
  const int lane = tid & 63;
  const int quad = lane >> 4;
  const int l15 = lane & 15;
  const int wm = wave & 1;
  const int wn = wave >> 1;

  // XCD-aware swizzle: 8 XCDs, contiguous chunk of 260 pairs per XCD.
  int bid = (int)blockIdx.x;
  bid = (bid & 7) * (NPAIR / 8) + (bid >> 3);

  // decode pair index -> (I, J), I <= J
  int b = bid, I = 0;
  while (b >= NB - I) { b -= NB - I; ++I; }
  const int J = I + b;
  const bool diag = (I == J);

  const int rowBase = I * BM;
  const int colBase = J * BN;

  // staging map: wave stages rows [wave*32 + j*16, +16); lane -> (row, 16B slot)
  // slot is XOR-swizzled within the 64B row via the K-tiled GLOBAL source
  // (within-64B permutation; LDS dest linear as global_load_lds requires).
  const int stR = lane >> 2;                                  // local row 0..15
  const int stRow = wave * 32 + stR;                          // tile row (j adds 16)
  const int stCol = ((lane & 3) ^ ((stR >> 1) & 3)) * 8;      // swizzled short off
  // read-side swizzle: same XOR keyed by the local row (= l15 for frag reads)
  const int swq = quad ^ ((l15 >> 1) & 3);

  f32x4 acc[4][4];
#pragma unroll
  for (int m = 0; m < 4; ++m)
#pragma unroll
    for (int n = 0; n < 4; ++n) acc[m][n] = {0.f, 0.f, 0.f, 0.f};

  auto stage = [&](int bsel, int kti) {  // kti = K-tile index (k/32)
    unsigned short* As = (unsigned short*)(smem + bsel * 16384);
    unsigned short* Bs = (unsigned short*)(smem + bsel * 16384 + 8192);
    const unsigned short* baseA = Hb + (size_t)(I * 32 + kti) * TILE_SH;
    const unsigned short* baseB = Hb + (size_t)(J * 32 + kti) * TILE_SH;
#pragma unroll
    for (int j = 0; j < 2; ++j) {
      const unsigned short* ga = baseA + (stRow + j * 16) * 32 + stCol;
      __builtin_amdgcn_global_load_lds(
          (const __attribute__((address_space(1))) void*)ga,
          (__attribute__((address_space(3))) void*)&As[(wave * 2 + j) * 512],
          16, 0, 0);
      const unsigned short* gb = baseB + (stRow + j * 16) * 32 + stCol;
      __builtin_amdgcn_global_load_lds(
          (const __attribute__((address_space(1))) void*)gb,
          (__attribute__((address_space(3))) void*)&Bs[(wave * 2 + j) * 512],
          16, 0, 0);
    }
  };

  // prologue: stage tile 0 into buffer 0, drain, then pipeline.
  stage(0, 0);
  __syncthreads();  // drains vmcnt (global_load_lds) + lgkm

  int cur = 0;
  for (int kti = 0; kti < NT; ++kti) {
    if (kti + 1 < NT) stage(cur ^ 1, kti + 1);  // prefetch next (issue only)

    const unsigned short* As = (const unsigned short*)(smem + cur * 16384);
    const unsigned short* Bs = (const unsigned short*)(smem + cur * 16384 + 8192);
    bfx8 a[4], bb[4];
#pragma unroll
    for (int m = 0; m < 4; ++m)
      a[m] = *(const bfx8*)&As[(wm * 64 + m * 16 + l15) * BK + swq * 8];
#pragma unroll
    for (int n = 0; n < 4; ++n)
      bb[n] = *(const bfx8*)&Bs[(wn * 64 + n * 16 + l15) * BK + swq * 8];
#pragma unroll
    for (int m = 0; m < 4; ++m)
#pragma unroll
      for (int n = 0; n < 4; ++n)
        acc[m][n] = __builtin_amdgcn_mfma_f32_16x16x32_bf16(a[m], bb[n], acc[m][n], 0, 0, 0);

    __syncthreads();  // one drain+barrier per K-step; prefetch had compute cover
    cur ^= 1;
  }

  // ---- epilogue: dist = xr + xc - 2*G; both-sided masked reductions ----
  // LDS scratch (staging buffers are free after the loop's final barrier):
  // rbuf[2(wn)][128(row)][3] = 768 floats; tbm/tb1/tb2 1024 floats each.
  float* rbuf = (float*)smem;
  float* tbm = ((float*)smem) + 768;
  float* tb1 = tbm + 1024;
  float* tb2 = tb1 + 1024;

  int lc[4]; float xc[4];
#pragma unroll
  for (int n = 0; n < 4; ++n) {
    const int col = colBase + wn * 64 + n * 16 + l15;
    lc[n] = lab[col];
    xc[n] = xn[col];
  }
  float tmaxp[4], tmn1[4], tmn2[4];
#pragma unroll
  for (int n = 0; n < 4; ++n) { tmaxp[n] = 0.f; tmn1[n] = kInf; tmn2[n] = kInf; }

  // per-m: compute 4 rows' stats, shuffle-merge over 16 col-lanes, park in LDS
#pragma unroll
  for (int m = 0; m < 4; ++m) {
    int lr4[4]; float xr4[4];
#pragma unroll
    for (int r = 0; r < 4; ++r) {
      const int row = rowBase + wm * 64 + m * 16 + quad * 4 + r;
      lr4[r] = lab[row];
      xr4[r] = xn[row];
    }
    float rmax[4], r1v[4], r2v[4];
#pragma unroll
    for (int r = 0; r < 4; ++r) { rmax[r] = 0.f; r1v[r] = kInf; r2v[r] = kInf; }

    if (!diag) {
#pragma unroll
      for (int n = 0; n < 4; ++n)
#pragma unroll
        for (int r = 0; r < 4; ++r) {
          const float d = fmaf(-2.f, acc[m][n][r], xr4[r] + xc[n]);
          const bool eq = (lr4[r] == lc[n]);
          const float pos = eq ? d : 0.f;
          const float dn = eq ? kInf : d;
          rmax[r] = fmaxf(rmax[r], pos);
          min2_insert(r1v[r], r2v[r], dn);
          tmaxp[n] = fmaxf(tmaxp[n], pos);
          min2_insert(tmn1[n], tmn2[n], dn);
        }
    } else {
#pragma unroll
      for (int n = 0; n < 4; ++n)
#pragma unroll
        for (int r = 0; r < 4; ++r) {
          // self-pair only possible on the diagonal tile
          const bool selfp = (wm == wn) && (m == n) && (quad * 4 + r == l15);
          const float d = fmaf(-2.f, acc[m][n][r], xr4[r] + xc[n]);
          const bool eq = (lr4[r] == lc[n]);
          const float pos = (eq && !selfp) ? d : 0.f;
          const float dn = eq ? kInf : d;  // self is eq -> excluded from negatives
          rmax[r] = fmaxf(rmax[r], pos);
          min2_insert(r1v[r], r2v[r], dn);
        }
    }

    // merge over the 16 column-lanes (lane bits 0..3)
#pragma unroll
    for (int off = 1; off < 16; off <<= 1) {
#pragma unroll
      for (int r = 0; r < 4; ++r) {
        const float om = __shfl_xor(rmax[r], off, 64);
        const float o1 = __shfl_xor(r1v[r], off, 64);
        const float o2 = __shfl_xor(r2v[r], off, 64);
        rmax[r] = fmaxf(rmax[r], om);
        min2_merge(r1v[r], r2v[r], o1, o2);
      }
    }
    if (l15 == 0) {
#pragma unroll
      for (int r = 0; r < 4; ++r) {
        const int row = wm * 64 + m * 16 + quad * 4 + r;
        rbuf[(wn * 128 + row) * 3 + 0] = rmax[r];
        rbuf[(wn * 128 + row) * 3 + 1] = r1v[r];
        rbuf[(wn * 128 + row) * 3 + 2] = r2v[r];
      }
    }
  }

  // col-side partials to LDS (proven r1 path; writes harmless on diag)
#pragma unroll
  for (int n = 0; n < 4; ++n) {
    const int idx = (((wm * 2 + wn) * 4 + quad) * 4 + n) * 16 + l15;
    tbm[idx] = tmaxp[n];
    tb1[idx] = tmn1[n];
    tb2[idx] = tmn2[n];
  }
  __syncthreads();

  // row side: 128 threads merge the two wn halves and write P[I][J]
  if (tid < 128) {
    const int row = tid;
    float M = fmaxf(rbuf[row * 3 + 0], rbuf[(128 + row) * 3 + 0]);
    float a1 = rbuf[row * 3 + 1], a2 = rbuf[row * 3 + 2];
    min2_merge(a1, a2, rbuf[(128 + row) * 3 + 1], rbuf[(128 + row) * 3 + 2]);
    const size_t p = ((size_t)(I * NB + J)) * 128 + row;
    wsMax[p] = M;
    wsM1[p] = a1;
    wsM2[p] = a2;
  }
  // transposed side: wm==0 waves merge tbuf over {wm2, quad} and write P[J][I]
  if (wm == 0 && !diag) {
    const int tn = lane >> 4;
    const int tl = lane & 15;
    float M = 0.f, a1 = kInf, a2 = kInf;
#pragma unroll
    for (int wm2 = 0; wm2 < 2; ++wm2)
#pragma unroll
      for (int q = 0; q < 4; ++q) {
        const int idx = (((wm2 * 2 + wn) * 4 + q) * 4 + tn) * 16 + tl;
        M = fmaxf(M, tbm[idx]);
        min2_merge(a1, a2, tb1[idx], tb2[idx]);
      }
    const size_t p = ((size_t)(J * NB + I)) * 128 + wn * 64 + lane;
    wsMax[p] = M;
    wsM1[p] = a1;
    wsM2[p] = a2;
  }
}

// ---------------- merge+final fused: per-row merge -> block sums -> ticket ----
// 64 blocks. Each merges its 128 rows over the 64 col-block partials, writes
// bsum/bcnt, fences, takes a ticket; the LAST block re-fences and does the
// deterministic serial sum + divide (same order as the old final_kernel).
__global__ __launch_bounds__(256) void merge_final_kernel(
    const float* __restrict__ wsMax, const float* __restrict__ wsM1,
    const float* __restrict__ wsM2, float* __restrict__ bsum,
    float* __restrict__ bcnt, unsigned int* __restrict__ gticket,
    float* __restrict__ out) {
  const int r = threadIdx.x & 127;
  const int h = threadIdx.x >> 7;
  const int bi = blockIdx.x;
  float mp = 0.f, m1 = kInf, m2 = kInf;
#pragma unroll 8
  for (int bj = h * 32; bj < h * 32 + 32; ++bj) {
    const size_t p = ((size_t)(bi * NB + bj)) * 128 + r;
    mp = fmaxf(mp, wsMax[p]);
    min2_merge(m1, m2, wsM1[p], wsM2[p]);
  }
  __shared__ float hmax[128], hm1[128], hm2[128];
  if (h == 1) { hmax[r] = mp; hm1[r] = m1; hm2[r] = m2; }
  __syncthreads();
  float ls = 0.f, lc = 0.f;
  if (h == 0) {
    mp = fmaxf(mp, hmax[r]);
    min2_merge(m1, m2, hm1[r], hm2[r]);
    const float loss = fmaxf(mp - m2 + kAlpha, 0.f);
    ls = (loss > kEps) ? loss : 0.f;
    lc = (loss > kEps) ? 1.f : 0.f;
  }
#pragma unroll
  for (int off = 32; off; off >>= 1) {
    ls += __shfl_down(ls, off, 64);
    lc += __shfl_down(lc, off, 64);
  }
  __shared__ float ss[2], sc[2];
  if (h == 0 && (threadIdx.x & 63) == 0) {
    ss[threadIdx.x >> 6] = ls;
    sc[threadIdx.x >> 6] = lc;
  }
  __syncthreads();
  if (threadIdx.x == 0) {
    bsum[bi] = ss[0] + ss[1];
    bcnt[bi] = sc[0] + sc[1];
    __threadfence();  // make bsum/bcnt device-visible before the ticket
    const unsigned int tk = atomicAdd(gticket, 1u);
    if (tk == NB - 1) {
      __threadfence();  // acquire: all other blocks' bsum/bcnt visible
      float s = 0.f, c = 0.f;
#pragma unroll 8
      for (int i = 0; i < NB; ++i) { s += bsum[i]; c += bcnt[i]; }
      out[0] = s / c;
    }
  }
}

// ---------------- launch ----------------
extern "C" void kernel_launch(void* const* d_in, const int* in_sizes, int n_in,
                              void* d_out, int out_size, void* d_ws, size_t ws_size,
                              hipStream_t stream) {
  (void)in_sizes; (void)n_in; (void)out_size; (void)ws_size;
  const float* H = (const float*)d_in[0];
  const int* lab = (const int*)d_in[1];
  float* out = (float*)d_out;

  char* ws = (char*)d_ws;
  unsigned short* Hb = (unsigned short*)ws;                              // 16 MB (K-tiled)
  float* xn = (float*)(ws + (size_t)Nn * Dd * sizeof(unsigned short));   // 32 KB
  float* wsMax = xn + Nn;                 // 64*64*128 = 512K floats = 2 MB
  float* wsM1 = wsMax + NB * NB * 128;
  float* wsM2 = wsM1 + NB * NB * 128;
  float* bsum = wsM2 + NB * NB * 128;     // 64 floats
  float* bcnt = bsum + NB;
  unsigned int* gticket = (unsigned int*)(bcnt + NB);

  prep_kernel<<<Nn / 32, 256, 0, stream>>>(H, Hb, xn, gticket);
  triplet_main<<<NPAIR, 256, 0, stream>>>(Hb, xn, lab, wsMax, wsM1, wsM2);
  merge_final_kernel<<<NB, 256, 0, stream>>>(wsMax, wsM1, wsM2, bsum, bcnt,
                                             gticket, out);
}